// Round 9
// baseline (141.217 us; speedup 1.0000x reference)
//
#include <hip/hip_runtime.h>
#include <hip/hip_cooperative_groups.h>

#define NB    8
#define NQL   2048
#define NKL   2048
#define DD    64
#define DVV   64
#define QT    64             // q rows per block (4 waves x 16 rows)
#define NQT   32             // NQL/QT
#define CHK   256            // keys per chunk (4 steps of 64)
#define MAXCH 8              // NKL/CHK
#define KSTEP 64
#define NUNITS 1152          // total active (b,qt,kc) units
#define NAU    960           // 4-step units
#define NCOMB  448           // combine tasks (224 tiles x 2 segs)

typedef __attribute__((ext_vector_type(8))) short bf16x8;
typedef __attribute__((ext_vector_type(4))) short bf16x4;
typedef __attribute__((ext_vector_type(2))) short bf16x2;
typedef __attribute__((ext_vector_type(4))) float f32x4;

#define L2E 1.44269504088896340736f

__device__ __forceinline__ unsigned short f2bf(float x) {
    union { float f; unsigned u; } v; v.f = x;
    unsigned r = v.u + 0x7FFFu + ((v.u >> 16) & 1u);
    return (unsigned short)(r >> 16);
}

// LDS swizzles (indices in shorts; rows are 64 shorts = 128 B).
__device__ __forceinline__ int kswz(int row, int col) {
    return row * 64 + (col ^ ((row & 7) << 3));
}
__device__ __forceinline__ int vswz(int dv, int col) {
    return dv * 64 + (col ^ ((((dv & 7) ^ ((dv >> 3) & 7))) << 3));
}

// ============ cooperative single-dispatch kernel ============
// Phase A: persistent blocks grid-stride the 1152 units with a balanced
// static schedule (units 0..959 = uniform 4-step chunks; 960..1151 = the
// 1-3-step diagonal chunks, 3 per trailing block). Inner loop = R3 verbatim.
// grid.sync() (one device-wide fence). Phase B: 448 combine tasks.
__global__ __launch_bounds__(256, 4)
void attn_coop(const float* __restrict__ Qg, const float* __restrict__ Kg,
               const float* __restrict__ Vg, float* __restrict__ Og,
               float* __restrict__ Mp, float* __restrict__ Lp,
               float* __restrict__ Op)
{
    const int G    = gridDim.x;
    const int tid  = threadIdx.x;
    const int wv   = tid >> 6;
    const int lane = tid & 63;
    const int c    = lane & 15;
    const int h    = lane >> 4;
    const int R0l  = 16 * wv;

    // staging maps (256 threads; 16 floats K, 16 floats V each)
    const int skr = tid >> 2;             // K row 0..63
    const int sdc = (tid & 3) * 16;       // K col base
    const int vkr = (tid >> 3) << 1;      // V key pair 0..62
    const int vdc = (tid & 7) * 8;        // V dv base 0..56

    __shared__ short Kl[2][64 * 64];
    __shared__ short Vl[2][64 * 64];
    __shared__ float scb[MAXCH][32];

    for (int u = blockIdx.x; u < NUNITS; u += G) {
        // ---- unit decode (closed-form balanced schedule)
        int b, qt, kc, nsteps;
        if (u < NAU) {                    // 4-step full chunks
            b = u / 120;
            int r = u % 120;
            int acc0 = 0; kc = 0; qt = 3;
#pragma unroll
            for (int j = 0; j < 8; ++j) {
                int cnt = 29 - 4 * j;     // # full chunks with kc=j per batch
                if (r >= acc0 && r < acc0 + cnt) { kc = j; qt = 4 * j + 3 + (r - acc0); }
                acc0 += cnt;
            }
            nsteps = 4;
        } else {                          // diagonal partial chunks
            int v = u - NAU;
            b = v / 24;
            int r = v % 24;
            qt = 4 * (r / 3) + (r % 3);   // qt with (qt+1)%4 != 0
            kc = (qt + 1) >> 2;
            nsteps = (qt + 1) & 3;        // 1..3
        }
        const int KC0  = kc * CHK;
        const int nch  = (qt + 4) >> 2;
        const int tile = b * NQT + qt;
        const int Q0   = qt * QT;

        const float* Qb = Qg + (size_t)b * NQL * DD;
        const float* Kb = Kg + (size_t)b * NKL * DD;
        const float* Vb = Vg + (size_t)b * NKL * DVV;

        __syncthreads();                  // LDS safe to overwrite

        f32x4 kr[4], vr[4];

        // Q fragments (B-operand), 1/8 folded. slot (h,j) = Q[row][dh*32+8h+j]
        bf16x8 qf[2];
#pragma unroll
        for (int dh = 0; dh < 2; ++dh) {
            const float* src = Qb + (size_t)(Q0 + R0l + c) * DD + dh * 32 + h * 8;
            f32x4 x0 = *(const f32x4*)(src);
            f32x4 x1 = *(const f32x4*)(src + 4);
            bf16x8 t;
#pragma unroll
            for (int j = 0; j < 4; ++j) {
                t[j]     = (short)f2bf(x0[j] * 0.125f);
                t[4 + j] = (short)f2bf(x1[j] * 0.125f);
            }
            qf[dh] = t;
        }

        // prologue: stage step 0
        {
            const float* kb0 = Kb + (size_t)(KC0 + skr) * DD + sdc;
            kr[0] = *(const f32x4*)(kb0);     kr[1] = *(const f32x4*)(kb0 + 4);
            kr[2] = *(const f32x4*)(kb0 + 8); kr[3] = *(const f32x4*)(kb0 + 12);
            const float* vb0 = Vb + (size_t)(KC0 + vkr) * DVV + vdc;
            vr[0] = *(const f32x4*)(vb0);       vr[1] = *(const f32x4*)(vb0 + 4);
            vr[2] = *(const f32x4*)(vb0 + DVV); vr[3] = *(const f32x4*)(vb0 + DVV + 4);
            short* Kd = Kl[0]; short* Vd = Vl[0];
#pragma unroll
            for (int i = 0; i < 4; ++i) {
                bf16x4 t;
#pragma unroll
                for (int j = 0; j < 4; ++j) t[j] = (short)f2bf(kr[i][j]);
                *(bf16x4*)(Kd + kswz(skr, sdc + 4 * i)) = t;
            }
#pragma unroll
            for (int j = 0; j < 8; ++j) {
                bf16x2 t;
                t[0] = (short)f2bf(vr[j >> 2][j & 3]);
                t[1] = (short)f2bf(vr[2 + (j >> 2)][j & 3]);
                *(bf16x2*)(Vd + vswz(vdc + j, vkr)) = t;
            }
        }
        __syncthreads();

        float m = -INFINITY, l = 0.0f;
        f32x4 acc[4];
        {
            f32x4 z = {0.f, 0.f, 0.f, 0.f};
#pragma unroll
            for (int s4 = 0; s4 < 4; ++s4) acc[s4] = z;
        }

        for (int s = 0; s < nsteps; ++s) {
            const int pb = s & 1;

            if (s + 1 < nsteps) {   // T14: issue next step's loads early
                const float* kb0 = Kb + (size_t)(KC0 + (s + 1) * KSTEP + skr) * DD + sdc;
                kr[0] = *(const f32x4*)(kb0);     kr[1] = *(const f32x4*)(kb0 + 4);
                kr[2] = *(const f32x4*)(kb0 + 8); kr[3] = *(const f32x4*)(kb0 + 12);
                const float* vb0 = Vb + (size_t)(KC0 + (s + 1) * KSTEP + vkr) * DVV + vdc;
                vr[0] = *(const f32x4*)(vb0);       vr[1] = *(const f32x4*)(vb0 + 4);
                vr[2] = *(const f32x4*)(vb0 + DVV); vr[3] = *(const f32x4*)(vb0 + DVV + 4);
            }

            const int kg0 = KC0 + s * KSTEP;
            if (kg0 <= Q0 + R0l + 15) {            // wave-active (uniform)
                const short* Kd = Kl[pb];
                const short* Vd = Vl[pb];

                f32x4 st[4];
                {
                    f32x4 z = {0.f, 0.f, 0.f, 0.f};
#pragma unroll
                    for (int t = 0; t < 4; ++t) st[t] = z;
                }
#pragma unroll
                for (int t = 0; t < 4; ++t)
#pragma unroll
                    for (int dh = 0; dh < 2; ++dh) {
                        bf16x8 kf = *(const bf16x8*)(Kd + kswz(16 * t + c, dh * 32 + h * 8));
                        st[t] = __builtin_amdgcn_mfma_f32_16x16x32_bf16(kf, qf[dh], st[t], 0, 0, 0);
                    }

                if (kg0 + KSTEP - 1 > Q0 + R0l) {   // diagonal: mask
                    const int qg = Q0 + R0l + c;
#pragma unroll
                    for (int t = 0; t < 4; ++t)
#pragma unroll
                        for (int r = 0; r < 4; ++r) {
                            int key = kg0 + 16 * t + 4 * h + r;
                            if (key > qg) st[t][r] = -1e9f;
                        }
                }

                float vmax = st[0][0];
#pragma unroll
                for (int t = 0; t < 4; ++t)
#pragma unroll
                    for (int r = 0; r < 4; ++r) vmax = fmaxf(vmax, st[t][r]);
                vmax = fmaxf(vmax, __shfl_xor(vmax, 16));
                vmax = fmaxf(vmax, __shfl_xor(vmax, 32));

                if (!__all(vmax - m <= 8.0f)) {     // defer-max (T13)
                    float mn    = fmaxf(m, vmax);
                    float alpha = exp2f((m - mn) * L2E);
                    l *= alpha;
#pragma unroll
                    for (int s4 = 0; s4 < 4; ++s4)
#pragma unroll
                        for (int r = 0; r < 4; ++r) acc[s4][r] *= alpha;
                    m = mn;
                }

                float p[4][4];
                float ps = 0.f;
#pragma unroll
                for (int t = 0; t < 4; ++t)
#pragma unroll
                    for (int r = 0; r < 4; ++r) {
                        p[t][r] = exp2f((st[t][r] - m) * L2E);
                        ps += p[t][r];
                    }
                ps += __shfl_xor(ps, 16);
                ps += __shfl_xor(ps, 32);
                l += ps;

                bf16x8 pf[2];
#pragma unroll
                for (int u2 = 0; u2 < 2; ++u2) {
                    bf16x8 t;
#pragma unroll
                    for (int j = 0; j < 8; ++j) t[j] = (short)f2bf(p[2 * u2 + (j >> 2)][j & 3]);
                    pf[u2] = t;
                }
#pragma unroll
                for (int s4 = 0; s4 < 4; ++s4)
#pragma unroll
                    for (int u2 = 0; u2 < 2; ++u2) {
                        bf16x4 lo = *(const bf16x4*)(Vd + vswz(c + 16 * s4, 32 * u2 + 4 * h));
                        bf16x4 hi = *(const bf16x4*)(Vd + vswz(c + 16 * s4, 32 * u2 + 16 + 4 * h));
                        bf16x8 vf = {lo[0], lo[1], lo[2], lo[3], hi[0], hi[1], hi[2], hi[3]};
                        acc[s4] = __builtin_amdgcn_mfma_f32_16x16x32_bf16(vf, pf[u2], acc[s4], 0, 0, 0);
                    }
            }

            if (s + 1 < nsteps) {   // write next step into other buffer
                short* Kd = Kl[(s + 1) & 1];
                short* Vd = Vl[(s + 1) & 1];
#pragma unroll
                for (int i = 0; i < 4; ++i) {
                    bf16x4 t;
#pragma unroll
                    for (int j = 0; j < 4; ++j) t[j] = (short)f2bf(kr[i][j]);
                    *(bf16x4*)(Kd + kswz(skr, sdc + 4 * i)) = t;
                }
#pragma unroll
                for (int j = 0; j < 8; ++j) {
                    bf16x2 t;
                    t[0] = (short)f2bf(vr[j >> 2][j & 3]);
                    t[1] = (short)f2bf(vr[2 + (j >> 2)][j & 3]);
                    *(bf16x2*)(Vd + vswz(vdc + j, vkr)) = t;
                }
                __syncthreads();
            }
        }

        // ---- epilogue: direct finalize or partial store
        const int q = R0l + c;
        if (nch == 1) {
            const float iv = 1.0f / l;
            float* dst = Og + ((size_t)b * NQL + Q0 + q) * DVV;
#pragma unroll
            for (int s4 = 0; s4 < 4; ++s4) {
                f32x4 t = acc[s4];
#pragma unroll
                for (int r = 0; r < 4; ++r) t[r] *= iv;
                *(f32x4*)(dst + 16 * s4 + 4 * h) = t;
            }
        } else {
            float* Opg = Op + ((size_t)tile * MAXCH + kc) * (QT * DVV);
#pragma unroll
            for (int s4 = 0; s4 < 4; ++s4)
                *(f32x4*)(Opg + (size_t)q * DVV + 16 * s4 + 4 * h) = acc[s4];
            if (h == 0) {
                Mp[((size_t)tile * MAXCH + kc) * QT + q] = m;
                Lp[((size_t)tile * MAXCH + kc) * QT + q] = l;
            }
        }
    }

    // ================= device-wide sync, then combine =================
    cooperative_groups::this_grid().sync();

    for (int t = blockIdx.x; t < NCOMB; t += G) {
        const int seg = t & 1;
        const int tl  = t >> 1;
        const int b   = tl / 28;
        const int qt  = 4 + tl % 28;
        const int tile = b * NQT + qt;
        const int nch  = (qt + 4) >> 2;
        const int r0   = seg * 32;

        __syncthreads();                  // scb reuse safety
        if (tid < 32) {
            const int row = r0 + tid;
            float M = -INFINITY;
            for (int ch = 0; ch < nch; ++ch)
                M = fmaxf(M, Mp[((size_t)tile * MAXCH + ch) * QT + row]);
            float den = 0.f;
            for (int ch = 0; ch < nch; ++ch) {
                float e = exp2f((Mp[((size_t)tile * MAXCH + ch) * QT + row] - M) * L2E);
                den += e * Lp[((size_t)tile * MAXCH + ch) * QT + row];
                scb[ch][tid] = e;
            }
            float iv = 1.0f / den;
            for (int ch = 0; ch < nch; ++ch) scb[ch][tid] *= iv;
        }
        __syncthreads();

        const float* Opt = Op + (size_t)tile * MAXCH * (QT * DVV) + (size_t)r0 * DVV;
        float* dst = Og + ((size_t)b * NQL + qt * QT + r0) * DVV;
#pragma unroll
        for (int j = 0; j < 8; ++j) {
            int f = j * 256 + tid;
            int row = f >> 6;
            float val = 0.f;
            for (int ch = 0; ch < nch; ++ch)
                val += scb[ch][row] * Opt[(size_t)ch * (QT * DVV) + f];
            dst[f] = val;
        }
    }
}

// ================= fallback phase 1 (R3 structure) =================
__global__ __launch_bounds__(256, 4)
void attn_part(const float* __restrict__ Qg, const float* __restrict__ Kg,
               const float* __restrict__ Vg, float* __restrict__ Og,
               float* __restrict__ Mp, float* __restrict__ Lp,
               float* __restrict__ Op)
{
    const int bid = blockIdx.x;
    const int kc  = bid & 7;
    const int qt  = (bid >> 3) & 31;
    const int b   = bid >> 8;
    const int nkeys = QT * (qt + 1);
    const int KC0   = kc * CHK;
    if (KC0 >= nkeys) return;
    const int nsteps = min(4, (nkeys - KC0) >> 6);
    const int nch    = (qt + 4) >> 2;
    const int tile   = b * NQT + qt;

    const int tid  = threadIdx.x;
    const int wv   = tid >> 6;
    const int lane = tid & 63;
    const int c    = lane & 15;
    const int h    = lane >> 4;
    const int Q0   = qt * QT;
    const int R0l  = 16 * wv;

    const float* Qb = Qg + (size_t)b * NQL * DD;
    const float* Kb = Kg + (size_t)b * NKL * DD;
    const float* Vb = Vg + (size_t)b * NKL * DVV;

    __shared__ short Kl[2][64 * 64];
    __shared__ short Vl[2][64 * 64];

    const int skr = tid >> 2;
    const int sdc = (tid & 3) * 16;
    const int vkr = (tid >> 3) << 1;
    const int vdc = (tid & 7) * 8;
    f32x4 kr[4], vr[4];

    bf16x8 qf[2];
#pragma unroll
    for (int dh = 0; dh < 2; ++dh) {
        const float* src = Qb + (size_t)(Q0 + R0l + c) * DD + dh * 32 + h * 8;
        f32x4 x0 = *(const f32x4*)(src);
        f32x4 x1 = *(const f32x4*)(src + 4);
        bf16x8 t;
#pragma unroll
        for (int j = 0; j < 4; ++j) {
            t[j]     = (short)f2bf(x0[j] * 0.125f);
            t[4 + j] = (short)f2bf(x1[j] * 0.125f);
        }
        qf[dh] = t;
    }

    {
        const float* kb0 = Kb + (size_t)(KC0 + skr) * DD + sdc;
        kr[0] = *(const f32x4*)(kb0);     kr[1] = *(const f32x4*)(kb0 + 4);
        kr[2] = *(const f32x4*)(kb0 + 8); kr[3] = *(const f32x4*)(kb0 + 12);
        const float* vb0 = Vb + (size_t)(KC0 + vkr) * DVV + vdc;
        vr[0] = *(const f32x4*)(vb0);       vr[1] = *(const f32x4*)(vb0 + 4);
        vr[2] = *(const f32x4*)(vb0 + DVV); vr[3] = *(const f32x4*)(vb0 + DVV + 4);
        short* Kd = Kl[0]; short* Vd = Vl[0];
#pragma unroll
        for (int i = 0; i < 4; ++i) {
            bf16x4 t;
#pragma unroll
            for (int j = 0; j < 4; ++j) t[j] = (short)f2bf(kr[i][j]);
            *(bf16x4*)(Kd + kswz(skr, sdc + 4 * i)) = t;
        }
#pragma unroll
        for (int j = 0; j < 8; ++j) {
            bf16x2 t;
            t[0] = (short)f2bf(vr[j >> 2][j & 3]);
            t[1] = (short)f2bf(vr[2 + (j >> 2)][j & 3]);
            *(bf16x2*)(Vd + vswz(vdc + j, vkr)) = t;
        }
    }
    __syncthreads();

    float m = -INFINITY, l = 0.0f;
    f32x4 acc[4];
    {
        f32x4 z = {0.f, 0.f, 0.f, 0.f};
#pragma unroll
        for (int s4 = 0; s4 < 4; ++s4) acc[s4] = z;
    }

    for (int s = 0; s < nsteps; ++s) {
        const int pb = s & 1;
        if (s + 1 < nsteps) {
            const float* kb0 = Kb + (size_t)(KC0 + (s + 1) * KSTEP + skr) * DD + sdc;
            kr[0] = *(const f32x4*)(kb0);     kr[1] = *(const f32x4*)(kb0 + 4);
            kr[2] = *(const f32x4*)(kb0 + 8); kr[3] = *(const f32x4*)(kb0 + 12);
            const float* vb0 = Vb + (size_t)(KC0 + (s + 1) * KSTEP + vkr) * DVV + vdc;
            vr[0] = *(const f32x4*)(vb0);       vr[1] = *(const f32x4*)(vb0 + 4);
            vr[2] = *(const f32x4*)(vb0 + DVV); vr[3] = *(const f32x4*)(vb0 + DVV + 4);
        }

        const int kg0 = KC0 + s * KSTEP;
        if (kg0 <= Q0 + R0l + 15) {
            const short* Kd = Kl[pb];
            const short* Vd = Vl[pb];
            f32x4 st[4];
            {
                f32x4 z = {0.f, 0.f, 0.f, 0.f};
#pragma unroll
                for (int t = 0; t < 4; ++t) st[t] = z;
            }
#pragma unroll
            for (int t = 0; t < 4; ++t)
#pragma unroll
                for (int dh = 0; dh < 2; ++dh) {
                    bf16x8 kf = *(const bf16x8*)(Kd + kswz(16 * t + c, dh * 32 + h * 8));
                    st[t] = __builtin_amdgcn_mfma_f32_16x16x32_bf16(kf, qf[dh], st[t], 0, 0, 0);
                }
            if (kg0 + KSTEP - 1 > Q0 + R0l) {
                const int qg = Q0 + R0l + c;
#pragma unroll
                for (int t = 0; t < 4; ++t)
#pragma unroll
                    for (int r = 0; r < 4; ++r) {
                        int key = kg0 + 16 * t + 4 * h + r;
                        if (key > qg) st[t][r] = -1e9f;
                    }
            }
            float vmax = st[0][0];
#pragma unroll
            for (int t = 0; t < 4; ++t)
#pragma unroll
                for (int r = 0; r < 4; ++r) vmax = fmaxf(vmax, st[t][r]);
            vmax = fmaxf(vmax, __shfl_xor(vmax, 16));
            vmax = fmaxf(vmax, __shfl_xor(vmax, 32));
            if (!__all(vmax - m <= 8.0f)) {
                float mn    = fmaxf(m, vmax);
                float alpha = exp2f((m - mn) * L2E);
                l *= alpha;
#pragma unroll
                for (int s4 = 0; s4 < 4; ++s4)
#pragma unroll
                    for (int r = 0; r < 4; ++r) acc[s4][r] *= alpha;
                m = mn;
            }
            float p[4][4];
            float ps = 0.f;
#pragma unroll
            for (int t = 0; t < 4; ++t)
#pragma unroll
                for (int r = 0; r < 4; ++r) {
                    p[t][r] = exp2f((st[t][r] - m) * L2E);
                    ps += p[t][r];
                }
            ps += __shfl_xor(ps, 16);
            ps += __shfl_xor(ps, 32);
            l += ps;
            bf16x8 pf[2];
#pragma unroll
            for (int u = 0; u < 2; ++u) {
                bf16x8 t;
#pragma unroll
                for (int j = 0; j < 8; ++j) t[j] = (short)f2bf(p[2 * u + (j >> 2)][j & 3]);
                pf[u] = t;
            }
#pragma unroll
            for (int s4 = 0; s4 < 4; ++s4)
#pragma unroll
                for (int u = 0; u < 2; ++u) {
                    bf16x4 lo = *(const bf16x4*)(Vd + vswz(c + 16 * s4, 32 * u + 4 * h));
                    bf16x4 hi = *(const bf16x4*)(Vd + vswz(c + 16 * s4, 32 * u + 16 + 4 * h));
                    bf16x8 vf = {lo[0], lo[1], lo[2], lo[3], hi[0], hi[1], hi[2], hi[3]};
                    acc[s4] = __builtin_amdgcn_mfma_f32_16x16x32_bf16(vf, pf[u], acc[s4], 0, 0, 0);
                }
        }

        if (s + 1 < nsteps) {
            short* Kd = Kl[(s + 1) & 1];
            short* Vd = Vl[(s + 1) & 1];
#pragma unroll
            for (int i = 0; i < 4; ++i) {
                bf16x4 t;
#pragma unroll
                for (int j = 0; j < 4; ++j) t[j] = (short)f2bf(kr[i][j]);
                *(bf16x4*)(Kd + kswz(skr, sdc + 4 * i)) = t;
            }
#pragma unroll
            for (int j = 0; j < 8; ++j) {
                bf16x2 t;
                t[0] = (short)f2bf(vr[j >> 2][j & 3]);
                t[1] = (short)f2bf(vr[2 + (j >> 2)][j & 3]);
                *(bf16x2*)(Vd + vswz(vdc + j, vkr)) = t;
            }
            __syncthreads();
        }
    }

    const int q = R0l + c;
    if (nch == 1) {
        const float iv = 1.0f / l;
        float* dst = Og + ((size_t)b * NQL + Q0 + q) * DVV;
#pragma unroll
        for (int s4 = 0; s4 < 4; ++s4) {
            f32x4 t = acc[s4];
#pragma unroll
            for (int r = 0; r < 4; ++r) t[r] *= iv;
            *(f32x4*)(dst + 16 * s4 + 4 * h) = t;
        }
        return;
    }
    float* Opg = Op + ((size_t)tile * MAXCH + kc) * (QT * DVV);
#pragma unroll
    for (int s4 = 0; s4 < 4; ++s4)
        *(f32x4*)(Opg + (size_t)q * DVV + 16 * s4 + 4 * h) = acc[s4];
    if (h == 0) {
        Mp[((size_t)tile * MAXCH + kc) * QT + q] = m;
        Lp[((size_t)tile * MAXCH + kc) * QT + q] = l;
    }
}

// ================= fallback phase 2 =================
__global__ __launch_bounds__(256)
void attn_comb(const float* __restrict__ Op, const float* __restrict__ Mp,
               const float* __restrict__ Lp, float* __restrict__ Og)
{
    const int seg  = blockIdx.x & 1;
    const int tile = blockIdx.x >> 1;
    const int qt   = tile & (NQT - 1);
    const int b    = tile >> 5;
    const int nch  = (qt + 4) >> 2;
    if (nch == 1) return;

    const int tid = threadIdx.x;
    const int r0  = seg * 32;
    __shared__ float scb[MAXCH][32];

    if (tid < 32) {
        const int row = r0 + tid;
        float M = -INFINITY;
        for (int ch = 0; ch < nch; ++ch)
            M = fmaxf(M, Mp[((size_t)tile * MAXCH + ch) * QT + row]);
        float den = 0.f;
        for (int ch = 0; ch < nch; ++ch) {
            float e = exp2f((Mp[((size_t)tile * MAXCH + ch) * QT + row] - M) * L2E);
            den += e * Lp[((size_t)tile * MAXCH + ch) * QT + row];
            scb[ch][tid] = e;
        }
        float iv = 1.0f / den;
        for (int ch = 0; ch < nch; ++ch) scb[ch][tid] *= iv;
    }
    __syncthreads();

    const float* Opt = Op + (size_t)tile * MAXCH * (QT * DVV) + (size_t)r0 * DVV;
    float* dst = Og + ((size_t)b * NQL + qt * QT + r0) * DVV;
#pragma unroll
    for (int j = 0; j < 8; ++j) {
        int f = j * 256 + tid;
        int row = f >> 6;
        float val = 0.f;
        for (int ch = 0; ch < nch; ++ch)
            val += scb[ch][row] * Opt[(size_t)ch * (QT * DVV) + f];
        dst[f] = val;
    }
}

extern "C" void kernel_launch(void* const* d_in, const int* in_sizes, int n_in,
                              void* d_out, int out_size, void* d_ws, size_t ws_size,
                              hipStream_t stream)
{
    (void)in_sizes; (void)n_in; (void)out_size;
    const float* Q = (const float*)d_in[0];
    const float* K = (const float*)d_in[1];
    const float* V = (const float*)d_in[2];
    float* O = (float*)d_out;

    const size_t ml_elems = (size_t)(NB * NQT) * MAXCH * QT;
    const size_t op_elems = (size_t)(NB * NQT) * MAXCH * QT * DVV;
    const size_t need = (2 * ml_elems + op_elems) * sizeof(float);
    if (ws_size < need) return;           // harness always provides enough

    float* Mp = (float*)d_ws;
    float* Lp = Mp + ml_elems;
    float* Op = Lp + ml_elems;

    // occupancy-derived cooperative grid (all blocks must be resident)
    int nb = 0;
    hipError_t oe = hipOccupancyMaxActiveBlocksPerMultiprocessor(
        &nb, reinterpret_cast<const void*>(&attn_coop), 256, 0);
    bool coop = (oe == hipSuccess && nb >= 2);

    if (coop) {
        int G = nb * 256;
        if (G > 1024) G = 1024;
        void* args[] = {(void*)&Q, (void*)&K, (void*)&V, (void*)&O,
                        (void*)&Mp, (void*)&Lp, (void*)&Op};
        hipError_t e = hipLaunchCooperativeKernel(
            reinterpret_cast<const void*>(&attn_coop),
            dim3(G), dim3(256), args, 0u, stream);
        if (e == hipSuccess) return;
    }

    // fallback: proven two-dispatch path (R3)
    attn_part<<<dim3(NB * NQT * MAXCH), dim3(256), 0, stream>>>(
        Q, K, V, O, Mp, Lp, Op);
    attn_comb<<<dim3(NB * NQT * 2), dim3(256), 0, stream>>>(Op, Mp, Lp, O);
}

// Round 10
// 50.116 us; speedup vs baseline: 2.8178x; 2.8178x over previous
//
#include <hip/hip_runtime.h>

#define NB    8
#define NQL   2048
#define NKL   2048
#define DD    64
#define DVV   64
#define QT    64             // q rows per block (4 waves x 16 rows)
#define NQT   32             // NQL/QT
#define KSTEP 64
#define PPB   119            // pieces per batch: sum ceil((qt+1)/5)
#define MAXCH 7              // max pieces per tile

typedef __attribute__((ext_vector_type(8))) short bf16x8;
typedef __attribute__((ext_vector_type(4))) short bf16x4;
typedef __attribute__((ext_vector_type(2))) short bf16x2;
typedef __attribute__((ext_vector_type(4))) float f32x4;

#define L2E 1.44269504088896340736f

__device__ __forceinline__ unsigned short f2bf(float x) {
    union { float f; unsigned u; } v; v.f = x;
    unsigned r = v.u + 0x7FFFu + ((v.u >> 16) & 1u);
    return (unsigned short)(r >> 16);
}

// LDS swizzles (indices in shorts; rows are 64 shorts = 128 B).
__device__ __forceinline__ int kswz(int row, int col) {
    return row * 64 + (col ^ ((row & 7) << 3));
}
__device__ __forceinline__ int vswz(int dv, int col) {
    return dv * 64 + (col ^ ((((dv & 7) ^ ((dv >> 3) & 7))) << 3));
}

// ================= Phase 1: partial flash attention =================
// grid = 952 = 8 batches x 119 pieces -> EXACTLY one scheduling round
// (<=1024 block slots at 4 blocks/CU). Each piece = <=5 contiguous 64-key
// steps of one (b,qt) tile; pieces per tile = ceil((qt+1)/5), balanced
// sizes base/base+1. Inner loop identical to R3/R8 (double-buffered LDS,
// T14 register prefetch, T5 setprio).
__global__ __launch_bounds__(256, 4)
void attn_part(const float* __restrict__ Qg, const float* __restrict__ Kg,
               const float* __restrict__ Vg, float* __restrict__ Og,
               float* __restrict__ Mp, float* __restrict__ Lp,
               float* __restrict__ Op)
{
    // ---- piece decode (wave-uniform SALU)
    const int bid = blockIdx.x;
    const int b   = bid / PPB;
    const int r   = bid - b * PPB;
    int qt = 0, P = 1, j = 0;
    {
        int cum = 0;
#pragma unroll
        for (int t = 0; t < 32; ++t) {
            int pc = (t + 5) / 5;             // ceil((t+1)/5)
            if (r >= cum && r < cum + pc) { qt = t; P = pc; j = r - cum; }
            cum += pc;
        }
    }
    const int n    = qt + 1;                  // total steps for this tile
    const int base = n / P;
    const int rem  = n - base * P;
    const int s0   = j * base + (j < rem ? j : rem);
    const int nsteps = base + (j < rem ? 1 : 0);
    const int KC0  = s0 * KSTEP;
    const int pidx = b * PPB + r;             // piece storage slot

    const int tid  = threadIdx.x;
    const int wv   = tid >> 6;
    const int lane = tid & 63;
    const int c    = lane & 15;
    const int h    = lane >> 4;
    const int Q0   = qt * QT;
    const int R0l  = 16 * wv;

    const float* Qb = Qg + (size_t)b * NQL * DD;
    const float* Kb = Kg + (size_t)b * NKL * DD;
    const float* Vb = Vg + (size_t)b * NKL * DVV;

    __shared__ short Kl[2][64 * 64];
    __shared__ short Vl[2][64 * 64];

    // staging maps (256 threads; 16 floats K, 16 floats V each)
    const int skr = tid >> 2;             // K row 0..63
    const int sdc = (tid & 3) * 16;       // K col base
    const int vkr = (tid >> 3) << 1;      // V key pair 0..62
    const int vdc = (tid & 7) * 8;        // V dv base 0..56
    f32x4 kr[4], vr[4];

    // Q fragments (B-operand), 1/8 folded. slot (h,j) = Q[row][dh*32+8h+j]
    bf16x8 qf[2];
#pragma unroll
    for (int dh = 0; dh < 2; ++dh) {
        const float* src = Qb + (size_t)(Q0 + R0l + c) * DD + dh * 32 + h * 8;
        f32x4 x0 = *(const f32x4*)(src);
        f32x4 x1 = *(const f32x4*)(src + 4);
        bf16x8 t;
#pragma unroll
        for (int jj = 0; jj < 4; ++jj) {
            t[jj]     = (short)f2bf(x0[jj] * 0.125f);
            t[4 + jj] = (short)f2bf(x1[jj] * 0.125f);
        }
        qf[dh] = t;
    }

    // prologue: stage step 0
    {
        const float* kb0 = Kb + (size_t)(KC0 + skr) * DD + sdc;
        kr[0] = *(const f32x4*)(kb0);     kr[1] = *(const f32x4*)(kb0 + 4);
        kr[2] = *(const f32x4*)(kb0 + 8); kr[3] = *(const f32x4*)(kb0 + 12);
        const float* vb0 = Vb + (size_t)(KC0 + vkr) * DVV + vdc;
        vr[0] = *(const f32x4*)(vb0);       vr[1] = *(const f32x4*)(vb0 + 4);
        vr[2] = *(const f32x4*)(vb0 + DVV); vr[3] = *(const f32x4*)(vb0 + DVV + 4);
        short* Kd = Kl[0]; short* Vd = Vl[0];
#pragma unroll
        for (int i = 0; i < 4; ++i) {
            bf16x4 t;
#pragma unroll
            for (int jj = 0; jj < 4; ++jj) t[jj] = (short)f2bf(kr[i][jj]);
            *(bf16x4*)(Kd + kswz(skr, sdc + 4 * i)) = t;
        }
#pragma unroll
        for (int jj = 0; jj < 8; ++jj) {
            bf16x2 t;
            t[0] = (short)f2bf(vr[jj >> 2][jj & 3]);
            t[1] = (short)f2bf(vr[2 + (jj >> 2)][jj & 3]);
            *(bf16x2*)(Vd + vswz(vdc + jj, vkr)) = t;
        }
    }
    __syncthreads();

    float m = -INFINITY, l = 0.0f;
    f32x4 acc[4];
    {
        f32x4 z = {0.f, 0.f, 0.f, 0.f};
#pragma unroll
        for (int s4 = 0; s4 < 4; ++s4) acc[s4] = z;
    }

    for (int s = 0; s < nsteps; ++s) {
        const int pb = s & 1;

        if (s + 1 < nsteps) {   // T14: issue next step's global loads early
            const float* kb0 = Kb + (size_t)(KC0 + (s + 1) * KSTEP + skr) * DD + sdc;
            kr[0] = *(const f32x4*)(kb0);     kr[1] = *(const f32x4*)(kb0 + 4);
            kr[2] = *(const f32x4*)(kb0 + 8); kr[3] = *(const f32x4*)(kb0 + 12);
            const float* vb0 = Vb + (size_t)(KC0 + (s + 1) * KSTEP + vkr) * DVV + vdc;
            vr[0] = *(const f32x4*)(vb0);       vr[1] = *(const f32x4*)(vb0 + 4);
            vr[2] = *(const f32x4*)(vb0 + DVV); vr[3] = *(const f32x4*)(vb0 + DVV + 4);
        }

        const int kg0 = KC0 + s * KSTEP;
        if (kg0 <= Q0 + R0l + 15) {            // wave-active (wave-uniform)
            const short* Kd = Kl[pb];
            const short* Vd = Vl[pb];

            f32x4 st[4];
            {
                f32x4 z = {0.f, 0.f, 0.f, 0.f};
#pragma unroll
                for (int t = 0; t < 4; ++t) st[t] = z;
            }
            __builtin_amdgcn_s_setprio(1);
#pragma unroll
            for (int t = 0; t < 4; ++t)
#pragma unroll
                for (int dh = 0; dh < 2; ++dh) {
                    bf16x8 kf = *(const bf16x8*)(Kd + kswz(16 * t + c, dh * 32 + h * 8));
                    st[t] = __builtin_amdgcn_mfma_f32_16x16x32_bf16(kf, qf[dh], st[t], 0, 0, 0);
                }
            __builtin_amdgcn_s_setprio(0);

            if (kg0 + KSTEP - 1 > Q0 + R0l) {   // diagonal step: mask
                const int qg = Q0 + R0l + c;
#pragma unroll
                for (int t = 0; t < 4; ++t)
#pragma unroll
                    for (int rr = 0; rr < 4; ++rr) {
                        int key = kg0 + 16 * t + 4 * h + rr;
                        if (key > qg) st[t][rr] = -1e9f;
                    }
            }

            float vmax = st[0][0];
#pragma unroll
            for (int t = 0; t < 4; ++t)
#pragma unroll
                for (int rr = 0; rr < 4; ++rr) vmax = fmaxf(vmax, st[t][rr]);
            vmax = fmaxf(vmax, __shfl_xor(vmax, 16));
            vmax = fmaxf(vmax, __shfl_xor(vmax, 32));

            if (!__all(vmax - m <= 8.0f)) {     // defer-max (T13)
                float mn    = fmaxf(m, vmax);
                float alpha = exp2f((m - mn) * L2E);
                l *= alpha;
#pragma unroll
                for (int s4 = 0; s4 < 4; ++s4)
#pragma unroll
                    for (int rr = 0; rr < 4; ++rr) acc[s4][rr] *= alpha;
                m = mn;
            }

            float p[4][4];
            float ps = 0.f;
#pragma unroll
            for (int t = 0; t < 4; ++t)
#pragma unroll
                for (int rr = 0; rr < 4; ++rr) {
                    p[t][rr] = exp2f((st[t][rr] - m) * L2E);
                    ps += p[t][rr];
                }
            ps += __shfl_xor(ps, 16);
            ps += __shfl_xor(ps, 32);
            l += ps;

            bf16x8 pf[2];
#pragma unroll
            for (int u = 0; u < 2; ++u) {
                bf16x8 t;
#pragma unroll
                for (int jj = 0; jj < 8; ++jj) t[jj] = (short)f2bf(p[2 * u + (jj >> 2)][jj & 3]);
                pf[u] = t;
            }
            __builtin_amdgcn_s_setprio(1);
#pragma unroll
            for (int s4 = 0; s4 < 4; ++s4)
#pragma unroll
                for (int u = 0; u < 2; ++u) {
                    bf16x4 lo = *(const bf16x4*)(Vd + vswz(c + 16 * s4, 32 * u + 4 * h));
                    bf16x4 hi = *(const bf16x4*)(Vd + vswz(c + 16 * s4, 32 * u + 16 + 4 * h));
                    bf16x8 vf = {lo[0], lo[1], lo[2], lo[3], hi[0], hi[1], hi[2], hi[3]};
                    acc[s4] = __builtin_amdgcn_mfma_f32_16x16x32_bf16(vf, pf[u], acc[s4], 0, 0, 0);
                }
            __builtin_amdgcn_s_setprio(0);
        }

        if (s + 1 < nsteps) {   // write next step into the other buffer
            short* Kd = Kl[(s + 1) & 1];
            short* Vd = Vl[(s + 1) & 1];
#pragma unroll
            for (int i = 0; i < 4; ++i) {
                bf16x4 t;
#pragma unroll
                for (int jj = 0; jj < 4; ++jj) t[jj] = (short)f2bf(kr[i][jj]);
                *(bf16x4*)(Kd + kswz(skr, sdc + 4 * i)) = t;
            }
#pragma unroll
            for (int jj = 0; jj < 8; ++jj) {
                bf16x2 t;
                t[0] = (short)f2bf(vr[jj >> 2][jj & 3]);
                t[1] = (short)f2bf(vr[2 + (jj >> 2)][jj & 3]);
                *(bf16x2*)(Vd + vswz(vdc + jj, vkr)) = t;
            }
            __syncthreads();
        }
    }

    // ---- epilogue: direct finalize (single-piece tile) or partial store
    const int q = R0l + c;                      // local q row
    if (P == 1) {
        const float iv = 1.0f / l;
        float* dst = Og + ((size_t)b * NQL + Q0 + q) * DVV;
#pragma unroll
        for (int s4 = 0; s4 < 4; ++s4) {
            f32x4 t = acc[s4];
#pragma unroll
            for (int rr = 0; rr < 4; ++rr) t[rr] *= iv;
            *(f32x4*)(dst + 16 * s4 + 4 * h) = t;
        }
        return;
    }

    float* Opg = Op + (size_t)pidx * (QT * DVV);
#pragma unroll
    for (int s4 = 0; s4 < 4; ++s4)
        *(f32x4*)(Opg + (size_t)q * DVV + 16 * s4 + 4 * h) = acc[s4];
    if (h == 0) {
        Mp[(size_t)pidx * QT + q] = m;
        Lp[(size_t)pidx * QT + q] = l;
    }
}

// ================= Phase 2: combine partials =================
// grid = 8*27*2 = 432; block (b, qt>=5, seg): 32 q-rows, all pieces.
__global__ __launch_bounds__(256)
void attn_comb(const float* __restrict__ Op, const float* __restrict__ Mp,
               const float* __restrict__ Lp, float* __restrict__ Og)
{
    const int seg = blockIdx.x & 1;
    const int t2  = blockIdx.x >> 1;
    const int b   = t2 / 27;
    const int qt  = 5 + (t2 - b * 27);
    const int nch = (qt + 5) / 5;             // ceil((qt+1)/5), 2..7
    int rbase = 0;
#pragma unroll
    for (int t = 0; t < 32; ++t) if (t < qt) rbase += (t + 5) / 5;
    const size_t p0 = (size_t)(b * PPB + rbase);

    const int tid = threadIdx.x;
    const int r0  = seg * 32;

    __shared__ float scb[MAXCH][32];

    if (tid < 32) {
        const int row = r0 + tid;
        float M = -INFINITY;
        for (int ch = 0; ch < nch; ++ch)
            M = fmaxf(M, Mp[(p0 + ch) * QT + row]);
        float den = 0.f;
        for (int ch = 0; ch < nch; ++ch) {
            float e = exp2f((Mp[(p0 + ch) * QT + row] - M) * L2E);
            den += e * Lp[(p0 + ch) * QT + row];
            scb[ch][tid] = e;
        }
        float iv = 1.0f / den;
        for (int ch = 0; ch < nch; ++ch) scb[ch][tid] *= iv;
    }
    __syncthreads();

    const float* Opt = Op + p0 * (QT * DVV) + (size_t)r0 * DVV;
    float* dst = Og + ((size_t)b * NQL + qt * QT + r0) * DVV;
#pragma unroll
    for (int jj = 0; jj < 8; ++jj) {
        int f = jj * 256 + tid;
        int row = f >> 6;
        float val = 0.f;
        for (int ch = 0; ch < nch; ++ch)
            val += scb[ch][row] * Opt[(size_t)ch * (QT * DVV) + f];
        dst[f] = val;
    }
}

// ================= fallback (no workspace): round-1 kernel =================
__global__ __launch_bounds__(256, 4)
void attn_fwd_fb(const float* __restrict__ Qg, const float* __restrict__ Kg,
                 const float* __restrict__ Vg, float* __restrict__ Og)
{
    const int tid  = threadIdx.x;
    const int wv   = tid >> 6;
    const int lane = tid & 63;
    const int c    = lane & 15;
    const int h    = lane >> 4;
    const int bid = blockIdx.x;
    const int b   = bid & 7;
    const int qt  = bid >> 3;
    const int q0  = qt << 4;
    const float* Qb = Qg + (size_t)b * NQL * DD;
    const float* Kb = Kg + (size_t)b * NKL * DD;
    const float* Vb = Vg + (size_t)b * NKL * DVV;
    bf16x8 qf[2];
#pragma unroll
    for (int dh = 0; dh < 2; ++dh) {
        const float* src = Qb + (size_t)(q0 + c) * DD + dh * 32 + h * 8;
        f32x4 x0 = *(const f32x4*)(src);
        f32x4 x1 = *(const f32x4*)(src + 4);
        bf16x8 t;
#pragma unroll
        for (int jj = 0; jj < 4; ++jj) {
            t[jj]     = (short)f2bf(x0[jj] * 0.125f);
            t[4 + jj] = (short)f2bf(x1[jj] * 0.125f);
        }
        qf[dh] = t;
    }
    float m = -INFINITY, l = 0.0f;
    f32x4 acc[4];
    {
        f32x4 z = {0.f, 0.f, 0.f, 0.f};
#pragma unroll
        for (int s = 0; s < 4; ++s) acc[s] = z;
    }
    const int nkt = (q0 + 47) >> 5;
    for (int kt = wv; kt < nkt; kt += 4) {
        const int kb = kt << 5;
        f32x4 st[2];
        {
            f32x4 z = {0.f, 0.f, 0.f, 0.f};
            st[0] = z; st[1] = z;
        }
#pragma unroll
        for (int t = 0; t < 2; ++t)
#pragma unroll
            for (int dh = 0; dh < 2; ++dh) {
                const float* src = Kb + (size_t)(kb + t * 16 + c) * DD + dh * 32 + h * 8;
                f32x4 x0 = *(const f32x4*)(src);
                f32x4 x1 = *(const f32x4*)(src + 4);
                bf16x8 kf;
#pragma unroll
                for (int jj = 0; jj < 4; ++jj) {
                    kf[jj]     = (short)f2bf(x0[jj]);
                    kf[4 + jj] = (short)f2bf(x1[jj]);
                }
                st[t] = __builtin_amdgcn_mfma_f32_16x16x32_bf16(kf, qf[dh], st[t], 0, 0, 0);
            }
        if (kb + 31 > q0) {
#pragma unroll
            for (int t = 0; t < 2; ++t)
#pragma unroll
                for (int rr = 0; rr < 4; ++rr) {
                    int key = kb + t * 16 + h * 4 + rr;
                    if (key > q0 + c) st[t][rr] = -1e9f;
                }
        }
        float vmax = st[0][0];
#pragma unroll
        for (int t = 0; t < 2; ++t)
#pragma unroll
            for (int rr = 0; rr < 4; ++rr) vmax = fmaxf(vmax, st[t][rr]);
        vmax = fmaxf(vmax, __shfl_xor(vmax, 16));
        vmax = fmaxf(vmax, __shfl_xor(vmax, 32));
        float mn    = fmaxf(m, vmax);
        float alpha = exp2f((m - mn) * L2E);
        float p[2][4];
        float ps = 0.f;
#pragma unroll
        for (int t = 0; t < 2; ++t)
#pragma unroll
            for (int rr = 0; rr < 4; ++rr) {
                p[t][rr] = exp2f((st[t][rr] - mn) * L2E);
                ps += p[t][rr];
            }
        ps += __shfl_xor(ps, 16);
        ps += __shfl_xor(ps, 32);
        l = l * alpha + ps;
        m = mn;
#pragma unroll
        for (int s = 0; s < 4; ++s)
#pragma unroll
            for (int rr = 0; rr < 4; ++rr) acc[s][rr] *= alpha;
        bf16x8 pf;
#pragma unroll
        for (int jj = 0; jj < 8; ++jj) pf[jj] = (short)f2bf(p[jj >> 2][jj & 3]);
        size_t vrow[8];
#pragma unroll
        for (int jj = 0; jj < 8; ++jj)
            vrow[jj] = (size_t)(kb + h * 4 + (jj & 3) + ((jj >> 2) << 4)) * DVV + c;
#pragma unroll
        for (int s = 0; s < 4; ++s) {
            bf16x8 vf;
#pragma unroll
            for (int jj = 0; jj < 8; ++jj) vf[jj] = (short)f2bf(Vb[vrow[jj] + s * 16]);
            acc[s] = __builtin_amdgcn_mfma_f32_16x16x32_bf16(vf, pf, acc[s], 0, 0, 0);
        }
    }
    __shared__ float Osc[4][64][17];
    __shared__ float Msc[4][16];
    __shared__ float Lsc[4][16];
#pragma unroll
    for (int s = 0; s < 4; ++s)
#pragma unroll
        for (int rr = 0; rr < 4; ++rr)
            Osc[wv][s * 16 + h * 4 + rr][c] = acc[s][rr];
    if (lane < 16) { Msc[wv][c] = m; Lsc[wv][c] = l; }
    __syncthreads();
#pragma unroll
    for (int ri = 0; ri < 4; ++ri) {
        const int q = wv * 4 + ri;
        float M = fmaxf(fmaxf(Msc[0][q], Msc[1][q]), fmaxf(Msc[2][q], Msc[3][q]));
        float val = 0.f, den = 0.f;
#pragma unroll
        for (int w2 = 0; w2 < 4; ++w2) {
            float sc = exp2f((Msc[w2][q] - M) * L2E);
            den += Lsc[w2][q] * sc;
            val += Osc[w2][lane][q] * sc;
        }
        Og[((size_t)b * NQL + q0 + q) * DVV + lane] = val / den;
    }
}

extern "C" void kernel_launch(void* const* d_in, const int* in_sizes, int n_in,
                              void* d_out, int out_size, void* d_ws, size_t ws_size,
                              hipStream_t stream)
{
    (void)in_sizes; (void)n_in; (void)out_size;
    const float* Q = (const float*)d_in[0];
    const float* K = (const float*)d_in[1];
    const float* V = (const float*)d_in[2];
    float* O = (float*)d_out;

    // ws layout (floats): Mp | Lp | Op, indexed by piece (8*119 pieces)
    const size_t npieces  = (size_t)NB * PPB;          // 952
    const size_t ml_elems = npieces * QT;              // 60928
    const size_t op_elems = npieces * QT * DVV;        // ~3.9M
    const size_t need = (2 * ml_elems + op_elems) * sizeof(float);

    if (ws_size >= need) {
        float* Mp = (float*)d_ws;
        float* Lp = Mp + ml_elems;
        float* Op = Lp + ml_elems;
        attn_part<<<dim3(NB * PPB), dim3(256), 0, stream>>>(
            Q, K, V, O, Mp, Lp, Op);
        attn_comb<<<dim3(NB * 27 * 2), dim3(256), 0, stream>>>(Op, Mp, Lp, O);
    } else {
        attn_fwd_fb<<<dim3(NB * (NQL / 16)), dim3(256), 0, stream>>>(Q, K, V, O);
    }
}

// Round 11
// 49.952 us; speedup vs baseline: 2.8271x; 1.0033x over previous
//
#include <hip/hip_runtime.h>

#define NB    8
#define NQL   2048
#define NKL   2048
#define DD    64
#define DVV   64
#define QT    64             // q rows per block (4 waves x 16 rows)
#define NQT   32             // NQL/QT
#define KSTEP 64
#define PPB   119            // pieces per batch: sum ceil((qt+1)/5)
#define MAXCH 7              // max pieces per tile
#define MAXST 5              // max steps per piece

typedef __attribute__((ext_vector_type(8))) short bf16x8;
typedef __attribute__((ext_vector_type(4))) short bf16x4;
typedef __attribute__((ext_vector_type(8))) unsigned short u16x8;
typedef __attribute__((ext_vector_type(4))) float f32x4;

#define L2E 1.44269504088896340736f

#define VMCNT4 asm volatile("s_waitcnt vmcnt(4)" ::: "memory")
#define VMCNT0 asm volatile("s_waitcnt vmcnt(0)" ::: "memory")
#define LGKM0  asm volatile("s_waitcnt lgkmcnt(0)" ::: "memory")

__device__ __forceinline__ unsigned short f2bf(float x) {
    union { float f; unsigned u; } v; v.f = x;
    unsigned r = v.u + 0x7FFFu + ((v.u >> 16) & 1u);
    return (unsigned short)(r >> 16);
}

// LDS swizzles (indices in shorts; rows are 64 shorts = 128 B).
__device__ __forceinline__ int kswz(int row, int col) {
    return row * 64 + (col ^ ((row & 7) << 3));
}
__device__ __forceinline__ int vswz(int dv, int col) {
    return dv * 64 + (col ^ ((((dv & 7) ^ ((dv >> 3) & 7))) << 3));
}

// ============ pre-pass: K -> bf16 (same layout), V -> bf16 transposed ============
// one dispatch: blocks 0..511 convert K (8 elems/thread); 512..767 transpose V.
__global__ __launch_bounds__(256)
void cvt_kv(const float* __restrict__ K, const float* __restrict__ V,
            unsigned short* __restrict__ Kw, unsigned short* __restrict__ Vt)
{
    const int bid = blockIdx.x;
    if (bid < 512) {
        size_t i = ((size_t)bid * 256 + threadIdx.x) * 8;
        f32x4 a = *(const f32x4*)(K + i);
        f32x4 b = *(const f32x4*)(K + i + 4);
        u16x8 o;
#pragma unroll
        for (int j = 0; j < 4; ++j) { o[j] = f2bf(a[j]); o[4 + j] = f2bf(b[j]); }
        *(u16x8*)(Kw + i) = o;
    } else {
        const int v  = bid - 512;            // 0..255
        const int b  = v >> 5;
        const int k0 = (v & 31) << 6;        // key chunk of 64
        __shared__ float tile[64][65];
        const float* Vb = V + ((size_t)b * NKL + k0) * DVV;
        const int col = threadIdx.x & 63;
        const int r4  = threadIdx.x >> 6;    // 0..3
#pragma unroll
        for (int i = 0; i < 16; ++i) {
            int r = i * 4 + r4;
            tile[r][col] = Vb[(size_t)r * DVV + col];
        }
        __syncthreads();
        unsigned short* Vtb = Vt + (size_t)b * DVV * NKL;
#pragma unroll
        for (int i = 0; i < 16; ++i) {
            int dv = i * 4 + r4;
            Vtb[(size_t)dv * NKL + k0 + col] = f2bf(tile[col][dv]);
        }
    }
}

// ================= Phase 1: partial flash attention =================
// grid = 952 balanced pieces (R10 schedule). Staging from pre-converted
// bf16 K / V^T: 4 x 16B loads/thread/step, DEPTH-2 register pipeline with
// counted vmcnt(4) + raw s_barrier (T3/T4) -- next-next step's loads stay
// in flight across the barrier instead of being drained to 0.
__global__ __launch_bounds__(256, 4)
void attn_part(const float* __restrict__ Qg,
               const unsigned short* __restrict__ Kw,
               const unsigned short* __restrict__ Vt,
               float* __restrict__ Og,
               float* __restrict__ Mp, float* __restrict__ Lp,
               float* __restrict__ Op)
{
    // ---- piece decode (wave-uniform SALU)
    const int bid = blockIdx.x;
    const int b   = bid / PPB;
    const int r   = bid - b * PPB;
    int qt = 0, P = 1, j = 0;
    {
        int cum = 0;
#pragma unroll
        for (int t = 0; t < 32; ++t) {
            int pc = (t + 5) / 5;
            if (r >= cum && r < cum + pc) { qt = t; P = pc; j = r - cum; }
            cum += pc;
        }
    }
    const int n      = qt + 1;
    const int base   = n / P;
    const int rem    = n - base * P;
    const int s0     = j * base + (j < rem ? j : rem);
    const int nsteps = base + (j < rem ? 1 : 0);        // 1..5
    const int KC0    = s0 * KSTEP;
    const int pidx   = b * PPB + r;

    const int tid  = threadIdx.x;
    const int wv   = tid >> 6;
    const int lane = tid & 63;
    const int c    = lane & 15;
    const int h    = lane >> 4;
    const int Q0   = qt * QT;
    const int R0l  = 16 * wv;

    const float*          Qb  = Qg + (size_t)b * NQL * DD;
    const unsigned short* Kwb = Kw + (size_t)b * NKL * DD;
    const unsigned short* Vtb = Vt + (size_t)b * DVV * NKL;

    __shared__ short Kl[2][64 * 64];
    __shared__ short Vl[2][64 * 64];

    // staging map: thread t handles row skr (K key-row / V dv-row), 16-short col base
    const int skr  = tid >> 2;           // 0..63
    const int sc16 = (tid & 3) * 16;     // 0,16,32,48 (shorts)

    struct Stage { bf16x8 k0, k1, v0, v1; };
    Stage rg[2];

    auto ISSUE = [&](int s, int pi) {
        const unsigned short* kp = Kwb + (size_t)(KC0 + s * KSTEP + skr) * 64 + sc16;
        rg[pi].k0 = *(const bf16x8*)(kp);
        rg[pi].k1 = *(const bf16x8*)(kp + 8);
        const unsigned short* vp = Vtb + (size_t)skr * NKL + KC0 + s * KSTEP + sc16;
        rg[pi].v0 = *(const bf16x8*)(vp);
        rg[pi].v1 = *(const bf16x8*)(vp + 8);
    };
    auto WRITE = [&](int pi, int buf) {
        *(bf16x8*)(&Kl[buf][0] + kswz(skr, sc16))     = rg[pi].k0;
        *(bf16x8*)(&Kl[buf][0] + kswz(skr, sc16 + 8)) = rg[pi].k1;
        *(bf16x8*)(&Vl[buf][0] + vswz(skr, sc16))     = rg[pi].v0;
        *(bf16x8*)(&Vl[buf][0] + vswz(skr, sc16 + 8)) = rg[pi].v1;
    };

    // Q fragments (B-operand), 1/8 folded. slot (h,j) = Q[row][dh*32+8h+j]
    bf16x8 qf[2];
#pragma unroll
    for (int dh = 0; dh < 2; ++dh) {
        const float* src = Qb + (size_t)(Q0 + R0l + c) * DD + dh * 32 + h * 8;
        f32x4 x0 = *(const f32x4*)(src);
        f32x4 x1 = *(const f32x4*)(src + 4);
        bf16x8 t;
#pragma unroll
        for (int jj = 0; jj < 4; ++jj) {
            t[jj]     = (short)f2bf(x0[jj] * 0.125f);
            t[4 + jj] = (short)f2bf(x1[jj] * 0.125f);
        }
        qf[dh] = t;
    }

    // ---- prologue: fill depth-2 pipe, stage step 0
    ISSUE(0, 0);
    if (nsteps > 1) { ISSUE(1, 1); VMCNT4; } else { VMCNT0; }
    WRITE(0, 0);
    LGKM0;
    __builtin_amdgcn_s_barrier();

    float m = -INFINITY, l = 0.0f;
    f32x4 acc[4];
    {
        f32x4 z = {0.f, 0.f, 0.f, 0.f};
#pragma unroll
        for (int s4 = 0; s4 < 4; ++s4) acc[s4] = z;
    }

#pragma unroll
    for (int s = 0; s < MAXST; ++s) {
        if (s < nsteps) {
            if (s + 2 < nsteps) ISSUE(s + 2, s & 1);   // rg[s&1] already consumed

            const int kg0 = KC0 + s * KSTEP;
            if (kg0 <= Q0 + R0l + 15) {                // wave-active (uniform)
                const short* Kd = &Kl[s & 1][0];
                const short* Vd = &Vl[s & 1][0];

                f32x4 st[4];
                {
                    f32x4 z = {0.f, 0.f, 0.f, 0.f};
#pragma unroll
                    for (int t = 0; t < 4; ++t) st[t] = z;
                }
                __builtin_amdgcn_s_setprio(1);
#pragma unroll
                for (int t = 0; t < 4; ++t)
#pragma unroll
                    for (int dh = 0; dh < 2; ++dh) {
                        bf16x8 kf = *(const bf16x8*)(Kd + kswz(16 * t + c, dh * 32 + h * 8));
                        st[t] = __builtin_amdgcn_mfma_f32_16x16x32_bf16(kf, qf[dh], st[t], 0, 0, 0);
                    }
                __builtin_amdgcn_s_setprio(0);

                if (kg0 + KSTEP - 1 > Q0 + R0l) {      // diagonal step: mask
                    const int qg = Q0 + R0l + c;
#pragma unroll
                    for (int t = 0; t < 4; ++t)
#pragma unroll
                        for (int rr = 0; rr < 4; ++rr) {
                            int key = kg0 + 16 * t + 4 * h + rr;
                            if (key > qg) st[t][rr] = -1e9f;
                        }
                }

                float vmax = st[0][0];
#pragma unroll
                for (int t = 0; t < 4; ++t)
#pragma unroll
                    for (int rr = 0; rr < 4; ++rr) vmax = fmaxf(vmax, st[t][rr]);
                vmax = fmaxf(vmax, __shfl_xor(vmax, 16));
                vmax = fmaxf(vmax, __shfl_xor(vmax, 32));

                if (!__all(vmax - m <= 8.0f)) {        // defer-max (T13)
                    float mn    = fmaxf(m, vmax);
                    float alpha = exp2f((m - mn) * L2E);
                    l *= alpha;
#pragma unroll
                    for (int s4 = 0; s4 < 4; ++s4)
#pragma unroll
                        for (int rr = 0; rr < 4; ++rr) acc[s4][rr] *= alpha;
                    m = mn;
                }

                float p[4][4];
                float ps = 0.f;
#pragma unroll
                for (int t = 0; t < 4; ++t)
#pragma unroll
                    for (int rr = 0; rr < 4; ++rr) {
                        p[t][rr] = exp2f((st[t][rr] - m) * L2E);
                        ps += p[t][rr];
                    }
                ps += __shfl_xor(ps, 16);
                ps += __shfl_xor(ps, 32);
                l += ps;

                bf16x8 pf[2];
#pragma unroll
                for (int u = 0; u < 2; ++u) {
                    bf16x8 t;
#pragma unroll
                    for (int jj = 0; jj < 8; ++jj) t[jj] = (short)f2bf(p[2 * u + (jj >> 2)][jj & 3]);
                    pf[u] = t;
                }
                __builtin_amdgcn_s_setprio(1);
#pragma unroll
                for (int s4 = 0; s4 < 4; ++s4)
#pragma unroll
                    for (int u = 0; u < 2; ++u) {
                        bf16x4 lo = *(const bf16x4*)(Vd + vswz(c + 16 * s4, 32 * u + 4 * h));
                        bf16x4 hi = *(const bf16x4*)(Vd + vswz(c + 16 * s4, 32 * u + 16 + 4 * h));
                        bf16x8 vf = {lo[0], lo[1], lo[2], lo[3], hi[0], hi[1], hi[2], hi[3]};
                        acc[s4] = __builtin_amdgcn_mfma_f32_16x16x32_bf16(vf, pf[u], acc[s4], 0, 0, 0);
                    }
                __builtin_amdgcn_s_setprio(0);
            }

            if (s + 1 < nsteps) {
                // counted wait: only the s+1 set must land; s+2's 4 loads stay in flight
                if (s + 2 < nsteps) { VMCNT4; } else { VMCNT0; }
                WRITE((s + 1) & 1, (s + 1) & 1);
                LGKM0;
                __builtin_amdgcn_s_barrier();
            }
        }
    }

    // ---- epilogue: direct finalize (single-piece tile) or partial store
    const int q = R0l + c;
    if (P == 1) {
        const float iv = 1.0f / l;
        float* dst = Og + ((size_t)b * NQL + Q0 + q) * DVV;
#pragma unroll
        for (int s4 = 0; s4 < 4; ++s4) {
            f32x4 t = acc[s4];
#pragma unroll
            for (int rr = 0; rr < 4; ++rr) t[rr] *= iv;
            *(f32x4*)(dst + 16 * s4 + 4 * h) = t;
        }
        return;
    }

    float* Opg = Op + (size_t)pidx * (QT * DVV);
#pragma unroll
    for (int s4 = 0; s4 < 4; ++s4)
        *(f32x4*)(Opg + (size_t)q * DVV + 16 * s4 + 4 * h) = acc[s4];
    if (h == 0) {
        Mp[(size_t)pidx * QT + q] = m;
        Lp[(size_t)pidx * QT + q] = l;
    }
}

// ================= Phase 2: combine partials (R10 verbatim) =================
__global__ __launch_bounds__(256)
void attn_comb(const float* __restrict__ Op, const float* __restrict__ Mp,
               const float* __restrict__ Lp, float* __restrict__ Og)
{
    const int seg = blockIdx.x & 1;
    const int t2  = blockIdx.x >> 1;
    const int b   = t2 / 27;
    const int qt  = 5 + (t2 - b * 27);
    const int nch = (qt + 5) / 5;
    int rbase = 0;
#pragma unroll
    for (int t = 0; t < 32; ++t) if (t < qt) rbase += (t + 5) / 5;
    const size_t p0 = (size_t)(b * PPB + rbase);

    const int tid = threadIdx.x;
    const int r0  = seg * 32;

    __shared__ float scb[MAXCH][32];

    if (tid < 32) {
        const int row = r0 + tid;
        float M = -INFINITY;
        for (int ch = 0; ch < nch; ++ch)
            M = fmaxf(M, Mp[(p0 + ch) * QT + row]);
        float den = 0.f;
        for (int ch = 0; ch < nch; ++ch) {
            float e = exp2f((Mp[(p0 + ch) * QT + row] - M) * L2E);
            den += e * Lp[(p0 + ch) * QT + row];
            scb[ch][tid] = e;
        }
        float iv = 1.0f / den;
        for (int ch = 0; ch < nch; ++ch) scb[ch][tid] *= iv;
    }
    __syncthreads();

    const float* Opt = Op + p0 * (QT * DVV) + (size_t)r0 * DVV;
    float* dst = Og + ((size_t)b * NQL + qt * QT + r0) * DVV;
#pragma unroll
    for (int jj = 0; jj < 8; ++jj) {
        int f = jj * 256 + tid;
        int row = f >> 6;
        float val = 0.f;
        for (int ch = 0; ch < nch; ++ch)
            val += scb[ch][row] * Opt[(size_t)ch * (QT * DVV) + f];
        dst[f] = val;
    }
}

// ================= fallback (no workspace): round-1 kernel =================
__global__ __launch_bounds__(256, 4)
void attn_fwd_fb(const float* __restrict__ Qg, const float* __restrict__ Kg,
                 const float* __restrict__ Vg, float* __restrict__ Og)
{
    const int tid  = threadIdx.x;
    const int wv   = tid >> 6;
    const int lane = tid & 63;
    const int c    = lane & 15;
    const int h    = lane >> 4;
    const int bid = blockIdx.x;
    const int b   = bid & 7;
    const int qt  = bid >> 3;
    const int q0  = qt << 4;
    const float* Qb = Qg + (size_t)b * NQL * DD;
    const float* Kb = Kg + (size_t)b * NKL * DD;
    const float* Vb = Vg + (size_t)b * NKL * DVV;
    bf16x8 qf[2];
#pragma unroll
    for (int dh = 0; dh < 2; ++dh) {
        const float* src = Qb + (size_t)(q0 + c) * DD + dh * 32 + h * 8;
        f32x4 x0 = *(const f32x4*)(src);
        f32x4 x1 = *(const f32x4*)(src + 4);
        bf16x8 t;
#pragma unroll
        for (int jj = 0; jj < 4; ++jj) {
            t[jj]     = (short)f2bf(x0[jj] * 0.125f);
            t[4 + jj] = (short)f2bf(x1[jj] * 0.125f);
        }
        qf[dh] = t;
    }
    float m = -INFINITY, l = 0.0f;
    f32x4 acc[4];
    {
        f32x4 z = {0.f, 0.f, 0.f, 0.f};
#pragma unroll
        for (int s = 0; s < 4; ++s) acc[s] = z;
    }
    const int nkt = (q0 + 47) >> 5;
    for (int kt = wv; kt < nkt; kt += 4) {
        const int kb = kt << 5;
        f32x4 st[2];
        {
            f32x4 z = {0.f, 0.f, 0.f, 0.f};
            st[0] = z; st[1] = z;
        }
#pragma unroll
        for (int t = 0; t < 2; ++t)
#pragma unroll
            for (int dh = 0; dh < 2; ++dh) {
                const float* src = Kb + (size_t)(kb + t * 16 + c) * DD + dh * 32 + h * 8;
                f32x4 x0 = *(const f32x4*)(src);
                f32x4 x1 = *(const f32x4*)(src + 4);
                bf16x8 kf;
#pragma unroll
                for (int jj = 0; jj < 4; ++jj) {
                    kf[jj]     = (short)f2bf(x0[jj]);
                    kf[4 + jj] = (short)f2bf(x1[jj]);
                }
                st[t] = __builtin_amdgcn_mfma_f32_16x16x32_bf16(kf, qf[dh], st[t], 0, 0, 0);
            }
        if (kb + 31 > q0) {
#pragma unroll
            for (int t = 0; t < 2; ++t)
#pragma unroll
                for (int rr = 0; rr < 4; ++rr) {
                    int key = kb + t * 16 + h * 4 + rr;
                    if (key > q0 + c) st[t][rr] = -1e9f;
                }
        }
        float vmax = st[0][0];
#pragma unroll
        for (int t = 0; t < 2; ++t)
#pragma unroll
            for (int rr = 0; rr < 4; ++rr) vmax = fmaxf(vmax, st[t][rr]);
        vmax = fmaxf(vmax, __shfl_xor(vmax, 16));
        vmax = fmaxf(vmax, __shfl_xor(vmax, 32));
        float mn    = fmaxf(m, vmax);
        float alpha = exp2f((m - mn) * L2E);
        float p[2][4];
        float ps = 0.f;
#pragma unroll
        for (int t = 0; t < 2; ++t)
#pragma unroll
            for (int rr = 0; rr < 4; ++rr) {
                p[t][rr] = exp2f((st[t][rr] - mn) * L2E);
                ps += p[t][rr];
            }
        ps += __shfl_xor(ps, 16);
        ps += __shfl_xor(ps, 32);
        l = l * alpha + ps;
        m = mn;
#pragma unroll
        for (int s = 0; s < 4; ++s)
#pragma unroll
            for (int rr = 0; rr < 4; ++rr) acc[s][rr] *= alpha;
        bf16x8 pf;
#pragma unroll
        for (int jj = 0; jj < 8; ++jj) pf[jj] = (short)f2bf(p[jj >> 2][jj & 3]);
        size_t vrow[8];
#pragma unroll
        for (int jj = 0; jj < 8; ++jj)
            vrow[jj] = (size_t)(kb + h * 4 + (jj & 3) + ((jj >> 2) << 4)) * DVV + c;
#pragma unroll
        for (int s = 0; s < 4; ++s) {
            bf16x8 vf;
#pragma unroll
            for (int jj = 0; jj < 8; ++jj) vf[jj] = (short)f2bf(Vb[vrow[jj] + s * 16]);
            acc[s] = __builtin_amdgcn_mfma_f32_16x16x32_bf16(vf, pf, acc[s], 0, 0, 0);
        }
    }
    __shared__ float Osc[4][64][17];
    __shared__ float Msc[4][16];
    __shared__ float Lsc[4][16];
#pragma unroll
    for (int s = 0; s < 4; ++s)
#pragma unroll
        for (int rr = 0; rr < 4; ++rr)
            Osc[wv][s * 16 + h * 4 + rr][c] = acc[s][rr];
    if (lane < 16) { Msc[wv][c] = m; Lsc[wv][c] = l; }
    __syncthreads();
#pragma unroll
    for (int ri = 0; ri < 4; ++ri) {
        const int q = wv * 4 + ri;
        float M = fmaxf(fmaxf(Msc[0][q], Msc[1][q]), fmaxf(Msc[2][q], Msc[3][q]));
        float val = 0.f, den = 0.f;
#pragma unroll
        for (int w2 = 0; w2 < 4; ++w2) {
            float sc = exp2f((Msc[w2][q] - M) * L2E);
            den += Lsc[w2][q] * sc;
            val += Osc[w2][lane][q] * sc;
        }
        Og[((size_t)b * NQL + q0 + q) * DVV + lane] = val / den;
    }
}

extern "C" void kernel_launch(void* const* d_in, const int* in_sizes, int n_in,
                              void* d_out, int out_size, void* d_ws, size_t ws_size,
                              hipStream_t stream)
{
    (void)in_sizes; (void)n_in; (void)out_size;
    const float* Q = (const float*)d_in[0];
    const float* K = (const float*)d_in[1];
    const float* V = (const float*)d_in[2];
    float* O = (float*)d_out;

    // ws layout: Mp | Lp | Op (floats) | Kw | Vt (bf16)
    const size_t npieces  = (size_t)NB * PPB;          // 952
    const size_t ml_elems = npieces * QT;              // 60928
    const size_t op_elems = npieces * QT * DVV;        // ~3.9M
    const size_t kv_elems = (size_t)NB * NKL * DD;     // 1M shorts each
    const size_t need = (2 * ml_elems + op_elems) * sizeof(float)
                      + 2 * kv_elems * sizeof(unsigned short);

    if (ws_size >= need) {
        float* Mp = (float*)d_ws;
        float* Lp = Mp + ml_elems;
        float* Op = Lp + ml_elems;
        unsigned short* Kw = (unsigned short*)(Op + op_elems);
        unsigned short* Vt = Kw + kv_elems;
        cvt_kv<<<dim3(768), dim3(256), 0, stream>>>(K, V, Kw, Vt);
        attn_part<<<dim3(NB * PPB), dim3(256), 0, stream>>>(
            Q, Kw, Vt, O, Mp, Lp, Op);
        attn_comb<<<dim3(NB * 27 * 2), dim3(256), 0, stream>>>(Op, Mp, Lp, O);
    } else {
        attn_fwd_fb<<<dim3(NB * (NQL / 16)), dim3(256), 0, stream>>>(Q, K, V, O);
    }
}